// Round 5
// baseline (3874.680 us; speedup 1.0000x reference)
//
#include <hip/hip_runtime.h>
#include <stdint.h>

#define V 4096
#define D 128
#define E 12288
#define NPAD 16384
#define HALF 8192
#define TARGET 2048
#define MAXM (V - TARGET)    // 2048 max merges
#define ROWU32 256           // 4096 fields * 2 bits = 256 u32 per row (1 KB)
#define CAP 16               // max candidates & accepts per round

// s_waitcnt imms (gfx9): bits 3:0 vmcnt lo, 6:4 expcnt, 11:8 lgkmcnt, 15:14 vmcnt hi
#define WAIT_VM0   0x0F70    // vmcnt(0) only
#define WAIT_LGKM0 0xC07F    // lgkmcnt(0) only

// ws layout (bytes)
#define WS_N      0u                            // V*ROWU32*4 = 4 MB (2-bit matrix)
#define WS_PRI    (V * ROWU32 * 4u)             // V float
#define WS_KEYS   (WS_PRI + V * 4u)             // NPAD u64
#define WS_PK     (WS_KEYS + NPAD * 8u)         // E u32 (sorted packed edges)
#define WS_PAIRS  (WS_PK + E * 4u)              // MAXM u32
#define WS_MCOUNT (WS_PAIRS + MAXM * 4u)        // 1 int
#define WS_ALIVE  (WS_MCOUNT + 16u)             // V u8

__device__ __forceinline__ unsigned getf(const uint4& r, int c) {
    unsigned lo = (c & 2) ? r.z : r.x;
    unsigned hi = (c & 2) ? r.w : r.y;
    return (c & 1) ? hi : lo;
}

__global__ void k_scatter(const int* __restrict__ edges, unsigned* __restrict__ n32) {
    int e = blockIdx.x * 256 + threadIdx.x;
    if (e < E) {
        int a = edges[e], b = edges[E + e];
        atomicOr(&n32[a * ROWU32 + (b >> 4)], 2u << ((b & 15) * 2));
        atomicOr(&n32[b * ROWU32 + (a >> 4)], 2u << ((a & 15) * 2));
    }
}

// numpy pairwise f32 sum for n=128 (matches np oracle reduction order)
__global__ void k_pri(const float* __restrict__ f, float* __restrict__ pri) {
    int v = blockIdx.x * 256 + threadIdx.x;
    if (v < V) {
        const float* p = f + v * D;
        float r[8];
#pragma unroll
        for (int j = 0; j < 8; j++) r[j] = __fmul_rn(p[j], p[j]);
        for (int i = 8; i < D; i += 8) {
#pragma unroll
            for (int j = 0; j < 8; j++)
                r[j] = __fadd_rn(r[j], __fmul_rn(p[i + j], p[i + j]));
        }
        float s01 = __fadd_rn(r[0], r[1]);
        float s23 = __fadd_rn(r[2], r[3]);
        float s45 = __fadd_rn(r[4], r[5]);
        float s67 = __fadd_rn(r[6], r[7]);
        pri[v] = __fadd_rn(__fadd_rn(s01, s23), __fadd_rn(s45, s67));
    }
}

__global__ void k_keys(const int* __restrict__ edges, const float* __restrict__ pri,
                       unsigned long long* __restrict__ keys) {
    int s = blockIdx.x * 256 + threadIdx.x;
    if (s < NPAD) {
        unsigned long long rec;
        if (s < E) {
            int a = edges[s], b = edges[E + s];
            float k = __fadd_rn(pri[a], pri[b]);   // epri >= 0 -> bits monotone
            rec = ((unsigned long long)__float_as_uint(k) << 32) | (unsigned)s;
        } else {
            rec = (0xFFFFFFFFull << 32) | (unsigned)s;
        }
        keys[s] = rec;
    }
}

// bitonic sort one 8192-element half in LDS; 2 blocks run concurrently
__launch_bounds__(1024)
__global__ void k_sort2(unsigned long long* __restrict__ keys) {
    __shared__ unsigned long long srt[HALF];
    const int tid = threadIdx.x;
    unsigned long long* base = keys + blockIdx.x * HALF;
    for (int s = tid; s < HALF; s += 1024) srt[s] = base[s];
    __syncthreads();
    for (int k = 2; k <= HALF; k <<= 1) {
        for (int j = k >> 1; j >= 1; j >>= 1) {
            for (int i = tid; i < HALF; i += 1024) {
                int ixj = i ^ j;
                if (ixj > i) {
                    unsigned long long x = srt[i], y = srt[ixj];
                    bool up = ((i & k) == 0);
                    if ((x > y) == up) { srt[i] = y; srt[ixj] = x; }
                }
            }
            __syncthreads();
        }
    }
    for (int s = tid; s < HALF; s += 1024) base[s] = srt[s];
}

// merge-path the two sorted halves; emit packed (v0<<16|v1) in global order
__launch_bounds__(64)
__global__ void k_mergepath(const unsigned long long* __restrict__ keys,
                            const int* __restrict__ edges, unsigned* __restrict__ pkG) {
    int t = blockIdx.x * 64 + threadIdx.x;
    if (t >= E / 64) return;
    const unsigned long long* A = keys;
    const unsigned long long* B = keys + HALF;
    int d = t * 64;
    int lo = d > HALF ? d - HALF : 0;
    int hi = d < HALF ? d : HALF;
    while (lo < hi) {
        int mid = (lo + hi) >> 1;
        if (A[mid] < B[d - 1 - mid]) lo = mid + 1; else hi = mid;
    }
    int ia = lo, ib = d - lo;
    for (int o = d; o < d + 64; o++) {
        bool takeA = (ib >= HALF) || (ia < HALF && A[ia] < B[ib]);
        unsigned long long r = takeA ? A[ia++] : B[ib++];
        int e = (int)(r & 0xFFFFFFFFull);
        int a = edges[e], b = edges[E + e];
        pkG[o] = ((unsigned)a << 16) | (unsigned)b;
    }
}

// ONE wave: windowed scan, replicated-VALU greedy accept, register/LDS state tracking
__launch_bounds__(64, 1)
__global__ void k_collapse(const unsigned* __restrict__ pkG, unsigned* n32,
                           unsigned* __restrict__ pairsG, int* __restrict__ mcountG,
                           uint8_t* __restrict__ aliveG, float* __restrict__ out) {
    __shared__ unsigned shPk[64];
    __shared__ unsigned shRR[CAP * ROWU32];   // 16 KB staged new rows
    __shared__ uint8_t alive[V];
    const int lane = threadIdx.x;
    for (int v = lane; v < V; v += 64) alive[v] = 1;
    __builtin_amdgcn_s_waitcnt(WAIT_LGKM0);

    int cnt = V, mcount = 0;
    bool done = false;

    for (int w = 0; w < E && !done; w += 64) {
        __builtin_amdgcn_s_waitcnt(WAIT_VM0);        // prior atomics visible in L2
        unsigned pkv = pkG[w + lane];
        const int a = (int)(pkv >> 16), b = (int)(pkv & 0xFFFFu);
        shPk[lane] = pkv;
        unsigned wv = *(volatile unsigned*)(n32 + a * ROWU32 + (b >> 4));
        unsigned fv = (wv >> ((b & 15) * 2)) & 3u;   // register-tracked 2-bit field
        __builtin_amdgcn_s_waitcnt(WAIT_LGKM0);
        bool av = alive[a] && alive[b];
        bool dec = false;

        for (int rnd = 0; rnd < 96 && !done; rnd++) {
            bool flag = !dec && av && (fv == 2u);
            unsigned long long mF = __ballot(flag);
            if (!mF) break;                           // all remaining lanes reject
            int limit = cnt - TARGET; if (limit > CAP) limit = CAP;

            // ---- candidate gather (flagged lanes in order; uniform) ----
            unsigned candPk[CAP]; int candLane[CAP];
            int F = 0;
            unsigned long long mIt = mF;
#pragma unroll
            for (int k = 0; k < CAP; k++) {
                int i = -1; unsigned cp = 0u;
                if (mIt) { i = __ffsll(mIt) - 1; mIt &= mIt - 1ull; F = k + 1; cp = shPk[i]; }
                candLane[k] = i; candPk[k] = cp;
            }
            int cutoff = mIt ? (__ffsll(mIt) - 1) : 64;

            // ---- replicated greedy scan (pure VALU; bloom is conservative->pending) ----
            unsigned long long B = 0ull;
            unsigned accBits = 0u; int nacc = 0;
            bool myPois = false; int myK = -1;
#pragma unroll
            for (int k = 0; k < CAP; k++) {
                if (k < F) {
                    int i = candLane[k];
                    if (nacc >= limit) { if (i < cutoff) cutoff = i; }
                    else {
                        int pa = (int)(candPk[k] >> 16), pb = (int)(candPk[k] & 0xFFFFu);
                        unsigned long long bits = (1ull << ((pa ^ (pa >> 6)) & 63)) |
                                                  (1ull << ((pb ^ (pb >> 6)) & 63));
                        bool conf = (B & bits) != 0ull;
                        if (!conf) { accBits |= 1u << k; nacc++; if (lane == i) myK = k; }
                        B |= bits;                    // accepted AND pending both block
                        if (i < lane && (pa == a || pa == b || pb == a || pb == b))
                            myPois = true;            // exact per-lane poison
                    }
                }
            }
            // reject: non-flagged, unpoisoned, before cutoff -> decided forever
            if (!dec && !flag && !myPois && lane < cutoff) dec = true;

            // ---- batched row loads for accepted merges ----
            __builtin_amdgcn_s_waitcnt(WAIT_VM0);    // last round's stores/atomics visible
            uint4 RA[CAP], RB[CAP];
#pragma unroll
            for (int k = 0; k < CAP; k++) {
                if ((accBits >> k) & 1u) {
                    int v0 = (int)(candPk[k] >> 16), v1 = (int)(candPk[k] & 0xFFFFu);
                    RA[k] = *((const uint4*)(n32 + v0 * ROWU32) + lane);
                    RB[k] = *((const uint4*)(n32 + v1 * ROWU32) + lane);
                }
            }

            // ---- hazard filter: demote y if {v0y,v1y} in N(v1x) (stale regs)
            //      or v0x in N(v1y) (same-word store-vs-XOR race) for earlier kept x ----
            unsigned keptBits = 0u;
            uint4 RBU = make_uint4(0u, 0u, 0u, 0u);   // union of kept rb rows
            uint4 MV0 = make_uint4(0u, 0u, 0u, 0u);   // mask of kept v0 field positions
#pragma unroll
            for (int k = 0; k < CAP; k++) {
                if ((accBits >> k) & 1u) {
                    int v0 = (int)(candPk[k] >> 16), v1 = (int)(candPk[k] & 0xFFFFu);
                    bool c = false;
                    if ((v0 >> 6) == lane)
                        c |= ((getf(RBU, (v0 >> 4) & 3) >> ((v0 & 15) * 2)) & 3u) != 0u;
                    if ((v1 >> 6) == lane)
                        c |= ((getf(RBU, (v1 >> 4) & 3) >> ((v1 & 15) * 2)) & 3u) != 0u;
                    c |= ((RB[k].x & MV0.x) | (RB[k].y & MV0.y) |
                          (RB[k].z & MV0.z) | (RB[k].w & MV0.w)) != 0u;
                    if (__ballot(c) == 0ull) {
                        keptBits |= 1u << k;
                        RBU.x |= RB[k].x; RBU.y |= RB[k].y;
                        RBU.z |= RB[k].z; RBU.w |= RB[k].w;
                        if ((v0 >> 6) == lane) {
                            int c4 = (v0 >> 4) & 3; unsigned bit = 3u << ((v0 & 15) * 2);
                            if (c4 == 0) MV0.x |= bit; else if (c4 == 1) MV0.y |= bit;
                            else if (c4 == 2) MV0.z |= bit; else MV0.w |= bit;
                        }
                    }
                }
            }
            if (myK >= 0 && ((keptBits >> myK) & 1u)) dec = true;  // my merge applies

            // ---- apply kept merges (disjoint, non-adjacent-hazard; commute) ----
#pragma unroll
            for (int k = 0; k < CAP; k++) {
                if ((keptBits >> k) & 1u) {
                    int v0 = (int)(candPk[k] >> 16), v1 = (int)(candPk[k] & 0xFFFFu);
                    uint4 ra = RA[k], rb = RB[k];
                    uint4 rr;
                    rr.x = ra.x | rb.x | ((ra.x & rb.x & 0xAAAAAAAAu) >> 1);
                    rr.y = ra.y | rb.y | ((ra.y & rb.y & 0xAAAAAAAAu) >> 1);
                    rr.z = ra.z | rb.z | ((ra.z & rb.z & 0xAAAAAAAAu) >> 1);
                    rr.w = ra.w | rb.w | ((ra.w & rb.w & 0xAAAAAAAAu) >> 1);
                    if ((v0 >> 6) == lane) {
                        int c4 = (v0 >> 4) & 3; unsigned m = ~(3u << ((v0 & 15) * 2));
                        if (c4 == 0) rr.x &= m; else if (c4 == 1) rr.y &= m;
                        else if (c4 == 2) rr.z &= m; else rr.w &= m;
                    }
                    if ((v1 >> 6) == lane) {
                        int c4 = (v1 >> 4) & 3; unsigned m = ~(3u << ((v1 & 15) * 2));
                        if (c4 == 0) rr.x &= m; else if (c4 == 1) rr.y &= m;
                        else if (c4 == 2) rr.z &= m; else rr.w &= m;
                    }
                    *((uint4*)(n32 + v0 * ROWU32) + lane) = rr;
                    *((uint4*)(shRR + k * ROWU32) + lane) = rr;
                    // column fixups via atomicXor (zero loads; symmetry gives old value)
                    int sh0 = (v0 & 15) * 2, wi0 = v0 >> 4;
#pragma unroll
                    for (int c = 0; c < 4; c++) {
                        unsigned bb = getf(rb, c);
                        if (!bb) continue;
                        unsigned aa = getf(ra, c), vv = getf(rr, c);
                        int xbase = (lane << 6) + (c << 4);
                        unsigned t = bb;
                        while (t) {
                            int q = (__ffs(t) - 1) >> 1;
                            t &= ~(3u << (q * 2));
                            int x = xbase + q;
                            if (x != v0 && x != v1) {
                                unsigned dx = (((aa >> (q * 2)) ^ (vv >> (q * 2))) & 3u) << sh0;
                                if (dx) atomicXor(n32 + x * ROWU32 + wi0, dx);
                            }
                        }
                    }
                    if (lane == 0) {
                        alive[v1] = 0;
                        pairsG[mcount] = ((unsigned)v0 << 16) | (unsigned)v1;
                    }
                    mcount++; cnt--;
                }
            }
            __builtin_amdgcn_s_waitcnt(WAIT_LGKM0);   // shRR + alive writes visible

            // ---- register state refresh (no global reload) ----
            int ja = -1, jb = -1;
#pragma unroll
            for (int k = 0; k < CAP; k++) {
                if ((keptBits >> k) & 1u) {
                    int v0 = (int)(candPk[k] >> 16), v1 = (int)(candPk[k] & 0xFFFFu);
                    if (a == v1 || b == v1) dec = true;     // endpoint died
                    if (a == v0) ja = k;                    // my row rewritten
                    if (b == v0) jb = k;                    // my column fixed up
                }
            }
            if (jb >= 0)      fv = (shRR[jb * ROWU32 + (a >> 4)] >> ((a & 15) * 2)) & 3u;
            else if (ja >= 0) fv = (shRR[ja * ROWU32 + (b >> 4)] >> ((b & 15) * 2)) & 3u;

            if (cnt == TARGET) done = true;
        }
    }

    for (int v = lane; v < V; v += 64) {
        uint8_t ao = alive[v];
        aliveG[v] = ao;
        out[V * D + v] = ao ? 1.0f : 0.0f;
    }
    if (lane == 0) { mcountG[0] = mcount; out[V * D + V] = (float)cnt; }
}

// Replay merge forest: per-vertex (root, weight) then scatter-add w*f[v] into out[root].
__launch_bounds__(256)
__global__ void k_apply(const float* __restrict__ f, const unsigned* __restrict__ pairsG,
                        const int* __restrict__ mcountG, float* __restrict__ out) {
    __shared__ unsigned pl[MAXM];
    __shared__ int rootL[256];
    __shared__ float wL[256];
    const int tid = threadIdx.x;
    const int mc = mcountG[0];
    for (int j = tid; j < mc; j += 256) pl[j] = pairsG[j];
    __syncthreads();
    int cur = blockIdx.x * 256 + tid;
    float w = 1.0f;
    for (int j = 0; j < mc; j++) {
        unsigned p = pl[j];
        int v0 = (int)(p >> 16), v1 = (int)(p & 0xFFFFu);
        if (cur == v1) { cur = v0; w *= 0.5f; }
        else if (cur == v0) w *= 0.5f;
    }
    rootL[tid] = cur;
    wL[tid] = w;
    __syncthreads();
    const int sub = tid >> 7;
    const int d = tid & 127;
    for (int s = 0; s < 256; s += 2) {
        int idx = s + sub;
        int vv = blockIdx.x * 256 + idx;
        atomicAdd(&out[rootL[idx] * D + d], wL[idx] * f[vv * D + d]);
    }
}

extern "C" void kernel_launch(void* const* d_in, const int* in_sizes, int n_in,
                              void* d_out, int out_size, void* d_ws, size_t ws_size,
                              hipStream_t stream) {
    (void)in_sizes; (void)n_in; (void)out_size; (void)ws_size;
    const float* features = (const float*)d_in[0];
    const int* edges = (const int*)d_in[1];
    uint8_t* ws = (uint8_t*)d_ws;
    unsigned* n32 = (unsigned*)(ws + WS_N);
    float* pri = (float*)(ws + WS_PRI);
    unsigned long long* keys = (unsigned long long*)(ws + WS_KEYS);
    unsigned* pkG = (unsigned*)(ws + WS_PK);
    unsigned* pairsG = (unsigned*)(ws + WS_PAIRS);
    int* mcountG = (int*)(ws + WS_MCOUNT);
    uint8_t* aliveG = ws + WS_ALIVE;
    float* out = (float*)d_out;

    hipMemsetAsync(n32, 0, (size_t)V * ROWU32 * 4, stream);
    hipMemsetAsync(out, 0, (size_t)V * D * sizeof(float), stream);
    k_pri<<<(V + 255) / 256, 256, 0, stream>>>(features, pri);
    k_scatter<<<(E + 255) / 256, 256, 0, stream>>>(edges, n32);
    k_keys<<<(NPAD + 255) / 256, 256, 0, stream>>>(edges, pri, keys);
    k_sort2<<<2, 1024, 0, stream>>>(keys);
    k_mergepath<<<(E / 64 + 63) / 64, 64, 0, stream>>>(keys, edges, pkG);
    k_collapse<<<1, 64, 0, stream>>>(pkG, n32, pairsG, mcountG, aliveG, out);
    k_apply<<<V / 256, 256, 0, stream>>>(features, pairsG, mcountG, out);
}

// Round 6
// 3825.645 us; speedup vs baseline: 1.0128x; 1.0128x over previous
//
#include <hip/hip_runtime.h>
#include <stdint.h>

#define V 4096
#define D 128
#define E 12288
#define NPAD 16384
#define HALF 8192
#define TARGET 2048
#define MAXM (V - TARGET)    // 2048 max merges
#define ROWU32 256           // 4096 fields * 2 bits = 256 u32 per row (1 KB)
#define CAP 16               // max accepts per round
#define SCANCAP 24           // max candidates examined per round

// s_waitcnt imms (gfx9): bits 3:0 vmcnt lo, 6:4 expcnt, 11:8 lgkmcnt, 15:14 vmcnt hi
#define WAIT_VM0   0x0F70    // vmcnt(0) only
#define WAIT_LGKM0 0xC07F    // lgkmcnt(0) only

// ws layout (bytes)
#define WS_N      0u                            // V*ROWU32*4 = 4 MB (2-bit matrix)
#define WS_PRI    (V * ROWU32 * 4u)             // V float
#define WS_KEYS   (WS_PRI + V * 4u)             // NPAD u64
#define WS_PK     (WS_KEYS + NPAD * 8u)         // E u32 (sorted packed edges)
#define WS_PAIRS  (WS_PK + E * 4u)              // MAXM u32
#define WS_MCOUNT (WS_PAIRS + MAXM * 4u)        // 1 int
#define WS_ALIVE  (WS_MCOUNT + 16u)             // V u8

typedef const __attribute__((address_space(1))) unsigned* gas1_t;
typedef __attribute__((address_space(3))) unsigned* las3_t;

__device__ __forceinline__ unsigned getf(const uint4& r, int c) {
    unsigned lo = (c & 2) ? r.z : r.x;
    unsigned hi = (c & 2) ? r.w : r.y;
    return (c & 1) ? hi : lo;
}
__device__ __forceinline__ void orf(uint4& r, int c, unsigned bits) {
    if (c == 0) r.x |= bits; else if (c == 1) r.y |= bits;
    else if (c == 2) r.z |= bits; else r.w |= bits;
}
__device__ __forceinline__ void andf(uint4& r, int c, unsigned msk) {
    if (c == 0) r.x &= msk; else if (c == 1) r.y &= msk;
    else if (c == 2) r.z &= msk; else r.w &= msk;
}

__global__ void k_scatter(const int* __restrict__ edges, unsigned* __restrict__ n32) {
    int e = blockIdx.x * 256 + threadIdx.x;
    if (e < E) {
        int a = edges[e], b = edges[E + e];
        atomicOr(&n32[a * ROWU32 + (b >> 4)], 2u << ((b & 15) * 2));
        atomicOr(&n32[b * ROWU32 + (a >> 4)], 2u << ((a & 15) * 2));
    }
}

// numpy pairwise f32 sum for n=128 (matches np oracle reduction order)
__global__ void k_pri(const float* __restrict__ f, float* __restrict__ pri) {
    int v = blockIdx.x * 256 + threadIdx.x;
    if (v < V) {
        const float* p = f + v * D;
        float r[8];
#pragma unroll
        for (int j = 0; j < 8; j++) r[j] = __fmul_rn(p[j], p[j]);
        for (int i = 8; i < D; i += 8) {
#pragma unroll
            for (int j = 0; j < 8; j++)
                r[j] = __fadd_rn(r[j], __fmul_rn(p[i + j], p[i + j]));
        }
        float s01 = __fadd_rn(r[0], r[1]);
        float s23 = __fadd_rn(r[2], r[3]);
        float s45 = __fadd_rn(r[4], r[5]);
        float s67 = __fadd_rn(r[6], r[7]);
        pri[v] = __fadd_rn(__fadd_rn(s01, s23), __fadd_rn(s45, s67));
    }
}

__global__ void k_keys(const int* __restrict__ edges, const float* __restrict__ pri,
                       unsigned long long* __restrict__ keys) {
    int s = blockIdx.x * 256 + threadIdx.x;
    if (s < NPAD) {
        unsigned long long rec;
        if (s < E) {
            int a = edges[s], b = edges[E + s];
            float k = __fadd_rn(pri[a], pri[b]);   // epri >= 0 -> bits monotone
            rec = ((unsigned long long)__float_as_uint(k) << 32) | (unsigned)s;
        } else {
            rec = (0xFFFFFFFFull << 32) | (unsigned)s;
        }
        keys[s] = rec;
    }
}

// bitonic sort one 8192-element half in LDS; 2 blocks run concurrently
__launch_bounds__(1024)
__global__ void k_sort2(unsigned long long* __restrict__ keys) {
    __shared__ unsigned long long srt[HALF];
    const int tid = threadIdx.x;
    unsigned long long* base = keys + blockIdx.x * HALF;
    for (int s = tid; s < HALF; s += 1024) srt[s] = base[s];
    __syncthreads();
    for (int k = 2; k <= HALF; k <<= 1) {
        for (int j = k >> 1; j >= 1; j >>= 1) {
            for (int i = tid; i < HALF; i += 1024) {
                int ixj = i ^ j;
                if (ixj > i) {
                    unsigned long long x = srt[i], y = srt[ixj];
                    bool up = ((i & k) == 0);
                    if ((x > y) == up) { srt[i] = y; srt[ixj] = x; }
                }
            }
            __syncthreads();
        }
    }
    for (int s = tid; s < HALF; s += 1024) base[s] = srt[s];
}

// merge-path the two sorted halves; emit packed (v0<<16|v1) in global order
__launch_bounds__(64)
__global__ void k_mergepath(const unsigned long long* __restrict__ keys,
                            const int* __restrict__ edges, unsigned* __restrict__ pkG) {
    int t = blockIdx.x * 64 + threadIdx.x;
    if (t >= E / 64) return;
    const unsigned long long* A = keys;
    const unsigned long long* B = keys + HALF;
    int d = t * 64;
    int lo = d > HALF ? d - HALF : 0;
    int hi = d < HALF ? d : HALF;
    while (lo < hi) {
        int mid = (lo + hi) >> 1;
        if (A[mid] < B[d - 1 - mid]) lo = mid + 1; else hi = mid;
    }
    int ia = lo, ib = d - lo;
    for (int o = d; o < d + 64; o++) {
        bool takeA = (ib >= HALF) || (ia < HALF && A[ia] < B[ib]);
        unsigned long long r = takeA ? A[ia++] : B[ib++];
        int e = (int)(r & 0xFFFFFFFFull);
        int a = edges[e], b = edges[E + e];
        pkG[o] = ((unsigned)a << 16) | (unsigned)b;
    }
}

// ONE wave: windowed monotone scan, LDS-resident rows (global_load_lds), lane-mask state
__launch_bounds__(64, 1)
__global__ void k_collapse(const unsigned* __restrict__ pkG, unsigned* n32,
                           unsigned* __restrict__ pairsG, int* __restrict__ mcountG,
                           uint8_t* __restrict__ aliveG, float* __restrict__ out) {
    __shared__ unsigned shRows[2 * CAP * ROWU32];   // 32 KB: slot 2k=row v0, 2k+1=row v1
    __shared__ uint8_t alive[V];
    const int lane = threadIdx.x;
    for (int v = lane; v < V; v += 64) alive[v] = 1;
    __builtin_amdgcn_s_waitcnt(WAIT_LGKM0);

    int cnt = V, mcount = 0;
    bool done = false;

    for (int w = 0; w < E && !done; w += 64) {
        __builtin_amdgcn_s_waitcnt(WAIT_VM0);        // prior window's stores visible
        unsigned pkv = pkG[w + lane];
        const int a = (int)(pkv >> 16), b = (int)(pkv & 0xFFFFu);
        unsigned wv = *(volatile unsigned*)(n32 + a * ROWU32 + (b >> 4));
        unsigned fv = (wv >> ((b & 15) * 2)) & 3u;   // register-tracked 2-bit field
        bool dec = !(alive[a] && alive[b]);          // monotone: false is final

        while (!done) {
            if (!dec && fv != 2u) dec = true;        // monotone reject (final)
            unsigned long long mF = __ballot(!dec);  // undecided == currently flagged
            if (!mF) break;
            int limit = cnt - TARGET; if (limit > CAP) limit = CAP;

            // ---- replicated greedy scan (shfl + 128-bit bloom; all lanes identical) ----
            unsigned long long accLanes = 0ull;
            unsigned long long B0 = 0ull, B1 = 0ull;
            int nacc = 0, scanned = 0;
            {
                unsigned long long mIt = mF;
                while (mIt && nacc < limit && scanned < SCANCAP) {
                    int i = __ffsll(mIt) - 1; mIt &= mIt - 1ull;
                    int ai = __shfl(a, i), bi = __shfl(b, i);
                    unsigned ha = ((unsigned)ai * 2654435761u) >> 25;   // 7-bit hash
                    unsigned hb = ((unsigned)bi * 2654435761u) >> 25;
                    unsigned long long m0 = 0ull, m1 = 0ull;
                    if (ha & 64) m1 |= 1ull << (ha & 63); else m0 |= 1ull << (ha & 63);
                    if (hb & 64) m1 |= 1ull << (hb & 63); else m0 |= 1ull << (hb & 63);
                    bool conf = ((B0 & m0) | (B1 & m1)) != 0ull;
                    if (!conf) { accLanes |= 1ull << i; nacc++; }
                    B0 |= m0; B1 |= m1;              // accepted AND pending both block
                    scanned++;
                }
            }

            // ---- async row fetch into LDS (no VGPR arrays; one wait for all) ----
            __builtin_amdgcn_s_waitcnt(WAIT_VM0);    // drain last round's stores/atomics
            {
                unsigned long long am = accLanes; int k = 0;
                while (am) {
                    int i = __ffsll(am) - 1; am &= am - 1ull;
                    int v0 = __shfl(a, i), v1 = __shfl(b, i);
                    __builtin_amdgcn_global_load_lds(
                        (gas1_t)(n32 + v0 * ROWU32 + lane * 4),
                        (las3_t)(shRows + (2 * k) * ROWU32), 16, 0, 0);
                    __builtin_amdgcn_global_load_lds(
                        (gas1_t)(n32 + v1 * ROWU32 + lane * 4),
                        (las3_t)(shRows + (2 * k + 1) * ROWU32), 16, 0, 0);
                    k++;
                }
            }
            __builtin_amdgcn_s_waitcnt(WAIT_VM0);    // rows landed in LDS
            __builtin_amdgcn_s_waitcnt(WAIT_LGKM0);

            // ---- exact hazard filter (adjacency & same-word races -> demote) ----
            unsigned long long keptLanes = 0ull;
            {
                uint4 RBU = make_uint4(0u, 0u, 0u, 0u);   // union of kept rb chunks (mine)
                uint4 MV0 = make_uint4(0u, 0u, 0u, 0u);   // kept v0 field positions (mine)
                unsigned long long am = accLanes; int k = 0;
                while (am) {
                    int i = __ffsll(am) - 1; am &= am - 1ull;
                    int v0 = __shfl(a, i), v1 = __shfl(b, i);
                    uint4 rb = *((const uint4*)(shRows + (2 * k + 1) * ROWU32) + lane);
                    bool c = false;
                    if ((v0 >> 6) == lane)
                        c |= ((getf(RBU, (v0 >> 4) & 3) >> ((v0 & 15) * 2)) & 3u) != 0u;
                    if ((v1 >> 6) == lane)
                        c |= ((getf(RBU, (v1 >> 4) & 3) >> ((v1 & 15) * 2)) & 3u) != 0u;
                    c |= ((rb.x & MV0.x) | (rb.y & MV0.y) |
                          (rb.z & MV0.z) | (rb.w & MV0.w)) != 0u;
                    if (__ballot(c) == 0ull) {
                        keptLanes |= 1ull << i;
                        RBU.x |= rb.x; RBU.y |= rb.y; RBU.z |= rb.z; RBU.w |= rb.w;
                        if ((v0 >> 6) == lane) orf(MV0, (v0 >> 4) & 3, 3u << ((v0 & 15) * 2));
                    }
                    k++;
                }
            }

            // ---- apply kept merges (disjoint + hazard-free -> commute exactly) ----
            {
                unsigned long long am = accLanes; int k = 0;
                while (am) {
                    int i = __ffsll(am) - 1; am &= am - 1ull;
                    if ((keptLanes >> i) & 1ull) {
                        int v0 = __shfl(a, i), v1 = __shfl(b, i);
                        uint4 ra = *((const uint4*)(shRows + (2 * k) * ROWU32) + lane);
                        uint4 rb = *((const uint4*)(shRows + (2 * k + 1) * ROWU32) + lane);
                        uint4 rr;
                        rr.x = ra.x | rb.x | ((ra.x & rb.x & 0xAAAAAAAAu) >> 1);
                        rr.y = ra.y | rb.y | ((ra.y & rb.y & 0xAAAAAAAAu) >> 1);
                        rr.z = ra.z | rb.z | ((ra.z & rb.z & 0xAAAAAAAAu) >> 1);
                        rr.w = ra.w | rb.w | ((ra.w & rb.w & 0xAAAAAAAAu) >> 1);
                        if ((v0 >> 6) == lane) andf(rr, (v0 >> 4) & 3, ~(3u << ((v0 & 15) * 2)));
                        if ((v1 >> 6) == lane) andf(rr, (v1 >> 4) & 3, ~(3u << ((v1 & 15) * 2)));
                        *((uint4*)(n32 + v0 * ROWU32) + lane) = rr;
                        *((uint4*)(shRows + (2 * k) * ROWU32) + lane) = rr;  // for refresh
                        // column fixups via atomicXor (symmetry gives old value; zero loads)
                        int sh0 = (v0 & 15) * 2, wi0 = v0 >> 4;
#pragma unroll
                        for (int c = 0; c < 4; c++) {
                            unsigned bb = getf(rb, c);
                            if (!bb) continue;
                            unsigned aa = getf(ra, c), vvv = getf(rr, c);
                            int xbase = (lane << 6) + (c << 4);
                            unsigned t = bb;
                            while (t) {
                                int q = (__ffs(t) - 1) >> 1;
                                t &= ~(3u << (q * 2));
                                int x = xbase + q;
                                if (x != v0 && x != v1) {
                                    unsigned dx =
                                        (((aa >> (q * 2)) ^ (vvv >> (q * 2))) & 3u) << sh0;
                                    if (dx) atomicXor(n32 + x * ROWU32 + wi0, dx);
                                }
                            }
                        }
                        if (lane == 0) {
                            alive[v1] = 0;
                            pairsG[mcount] = ((unsigned)v0 << 16) | (unsigned)v1;
                        }
                        mcount++; cnt--;
                    }
                    k++;
                }
            }
            __builtin_amdgcn_s_waitcnt(WAIT_LGKM0);  // rr in LDS + alive visible

            // ---- register state refresh (shfl + <=1 LDS read; no global reload) ----
            {
                int slot = -1, fld = 0;
                unsigned long long am = accLanes; int k = 0;
                while (am) {
                    int i = __ffsll(am) - 1; am &= am - 1ull;
                    if ((keptLanes >> i) & 1ull) {
                        int v0 = __shfl(a, i), v1 = __shfl(b, i);
                        if (a == v1 || b == v1) dec = true;   // endpoint died (final)
                        if (lane == i) dec = true;            // my merge applied
                        if (b == v0) { slot = 2 * k; fld = a; }   // column fixup on my word
                        else if (a == v0) { slot = 2 * k; fld = b; } // my row rewritten
                    }
                    k++;
                }
                if (slot >= 0 && !dec)
                    fv = (shRows[slot * ROWU32 + (fld >> 4)] >> ((fld & 15) * 2)) & 3u;
            }
            if (cnt == TARGET) done = true;
        }
    }

    for (int v = lane; v < V; v += 64) {
        uint8_t ao = alive[v];
        aliveG[v] = ao;
        out[V * D + v] = ao ? 1.0f : 0.0f;
    }
    if (lane == 0) { mcountG[0] = mcount; out[V * D + V] = (float)cnt; }
}

// Replay merge forest: per-vertex (root, weight) then scatter-add w*f[v] into out[root].
__launch_bounds__(256)
__global__ void k_apply(const float* __restrict__ f, const unsigned* __restrict__ pairsG,
                        const int* __restrict__ mcountG, float* __restrict__ out) {
    __shared__ unsigned pl[MAXM];
    __shared__ int rootL[256];
    __shared__ float wL[256];
    const int tid = threadIdx.x;
    const int mc = mcountG[0];
    for (int j = tid; j < mc; j += 256) pl[j] = pairsG[j];
    __syncthreads();
    int cur = blockIdx.x * 256 + tid;
    float w = 1.0f;
    for (int j = 0; j < mc; j++) {
        unsigned p = pl[j];
        int v0 = (int)(p >> 16), v1 = (int)(p & 0xFFFFu);
        if (cur == v1) { cur = v0; w *= 0.5f; }
        else if (cur == v0) w *= 0.5f;
    }
    rootL[tid] = cur;
    wL[tid] = w;
    __syncthreads();
    const int sub = tid >> 7;
    const int d = tid & 127;
    for (int s = 0; s < 256; s += 2) {
        int idx = s + sub;
        int vv = blockIdx.x * 256 + idx;
        atomicAdd(&out[rootL[idx] * D + d], wL[idx] * f[vv * D + d]);
    }
}

extern "C" void kernel_launch(void* const* d_in, const int* in_sizes, int n_in,
                              void* d_out, int out_size, void* d_ws, size_t ws_size,
                              hipStream_t stream) {
    (void)in_sizes; (void)n_in; (void)out_size; (void)ws_size;
    const float* features = (const float*)d_in[0];
    const int* edges = (const int*)d_in[1];
    uint8_t* ws = (uint8_t*)d_ws;
    unsigned* n32 = (unsigned*)(ws + WS_N);
    float* pri = (float*)(ws + WS_PRI);
    unsigned long long* keys = (unsigned long long*)(ws + WS_KEYS);
    unsigned* pkG = (unsigned*)(ws + WS_PK);
    unsigned* pairsG = (unsigned*)(ws + WS_PAIRS);
    int* mcountG = (int*)(ws + WS_MCOUNT);
    uint8_t* aliveG = ws + WS_ALIVE;
    float* out = (float*)d_out;

    hipMemsetAsync(n32, 0, (size_t)V * ROWU32 * 4, stream);
    hipMemsetAsync(out, 0, (size_t)V * D * sizeof(float), stream);
    k_pri<<<(V + 255) / 256, 256, 0, stream>>>(features, pri);
    k_scatter<<<(E + 255) / 256, 256, 0, stream>>>(edges, n32);
    k_keys<<<(NPAD + 255) / 256, 256, 0, stream>>>(edges, pri, keys);
    k_sort2<<<2, 1024, 0, stream>>>(keys);
    k_mergepath<<<(E / 64 + 63) / 64, 64, 0, stream>>>(keys, edges, pkG);
    k_collapse<<<1, 64, 0, stream>>>(pkG, n32, pairsG, mcountG, aliveG, out);
    k_apply<<<V / 256, 256, 0, stream>>>(features, pairsG, mcountG, out);
}

// Round 7
// 3245.921 us; speedup vs baseline: 1.1937x; 1.1786x over previous
//
#include <hip/hip_runtime.h>
#include <stdint.h>

#define V 4096
#define D 128
#define E 12288
#define NPAD 16384
#define HALF 8192
#define TARGET 2048
#define MAXM (V - TARGET)    // 2048 max merges
#define ROWU32 256           // 4096 fields * 2 bits = 256 u32 per row (1 KB)
#define CAP 16               // max accepts per round

// s_waitcnt imms (gfx9): bits 3:0 vmcnt lo, 6:4 expcnt, 11:8 lgkmcnt, 15:14 vmcnt hi
#define WAIT_VM0   0x0F70    // vmcnt(0) only
#define WAIT_LGKM0 0xC07F    // lgkmcnt(0) only

// ws layout (bytes)
#define WS_N      0u                            // V*ROWU32*4 = 4 MB (2-bit matrix)
#define WS_PRI    (V * ROWU32 * 4u)             // V float
#define WS_KEYS   (WS_PRI + V * 4u)             // NPAD u64
#define WS_PK     (WS_KEYS + NPAD * 8u)         // E u32 (sorted packed edges)
#define WS_PAIRS  (WS_PK + E * 4u)              // MAXM u32
#define WS_MCOUNT (WS_PAIRS + MAXM * 4u)        // 1 int
#define WS_ALIVE  (WS_MCOUNT + 16u)             // V u8

typedef const __attribute__((address_space(1))) unsigned* gas1_t;
typedef __attribute__((address_space(3))) unsigned* las3_t;

__device__ __forceinline__ unsigned getf(const uint4& r, int c) {
    unsigned lo = (c & 2) ? r.z : r.x;
    unsigned hi = (c & 2) ? r.w : r.y;
    return (c & 1) ? hi : lo;
}
__device__ __forceinline__ void andf(uint4& r, int c, unsigned msk) {
    if (c == 0) r.x &= msk; else if (c == 1) r.y &= msk;
    else if (c == 2) r.z &= msk; else r.w &= msk;
}

__global__ void k_scatter(const int* __restrict__ edges, unsigned* __restrict__ n32) {
    int e = blockIdx.x * 256 + threadIdx.x;
    if (e < E) {
        int a = edges[e], b = edges[E + e];
        atomicOr(&n32[a * ROWU32 + (b >> 4)], 2u << ((b & 15) * 2));
        atomicOr(&n32[b * ROWU32 + (a >> 4)], 2u << ((a & 15) * 2));
    }
}

// numpy pairwise f32 sum for n=128 (matches np oracle reduction order)
__global__ void k_pri(const float* __restrict__ f, float* __restrict__ pri) {
    int v = blockIdx.x * 256 + threadIdx.x;
    if (v < V) {
        const float* p = f + v * D;
        float r[8];
#pragma unroll
        for (int j = 0; j < 8; j++) r[j] = __fmul_rn(p[j], p[j]);
        for (int i = 8; i < D; i += 8) {
#pragma unroll
            for (int j = 0; j < 8; j++)
                r[j] = __fadd_rn(r[j], __fmul_rn(p[i + j], p[i + j]));
        }
        float s01 = __fadd_rn(r[0], r[1]);
        float s23 = __fadd_rn(r[2], r[3]);
        float s45 = __fadd_rn(r[4], r[5]);
        float s67 = __fadd_rn(r[6], r[7]);
        pri[v] = __fadd_rn(__fadd_rn(s01, s23), __fadd_rn(s45, s67));
    }
}

__global__ void k_keys(const int* __restrict__ edges, const float* __restrict__ pri,
                       unsigned long long* __restrict__ keys) {
    int s = blockIdx.x * 256 + threadIdx.x;
    if (s < NPAD) {
        unsigned long long rec;
        if (s < E) {
            int a = edges[s], b = edges[E + s];
            float k = __fadd_rn(pri[a], pri[b]);   // epri >= 0 -> bits monotone
            rec = ((unsigned long long)__float_as_uint(k) << 32) | (unsigned)s;
        } else {
            rec = (0xFFFFFFFFull << 32) | (unsigned)s;
        }
        keys[s] = rec;
    }
}

// bitonic sort one 8192-element half in LDS; 2 blocks run concurrently
__launch_bounds__(1024)
__global__ void k_sort2(unsigned long long* __restrict__ keys) {
    __shared__ unsigned long long srt[HALF];
    const int tid = threadIdx.x;
    unsigned long long* base = keys + blockIdx.x * HALF;
    for (int s = tid; s < HALF; s += 1024) srt[s] = base[s];
    __syncthreads();
    for (int k = 2; k <= HALF; k <<= 1) {
        for (int j = k >> 1; j >= 1; j >>= 1) {
            for (int i = tid; i < HALF; i += 1024) {
                int ixj = i ^ j;
                if (ixj > i) {
                    unsigned long long x = srt[i], y = srt[ixj];
                    bool up = ((i & k) == 0);
                    if ((x > y) == up) { srt[i] = y; srt[ixj] = x; }
                }
            }
            __syncthreads();
        }
    }
    for (int s = tid; s < HALF; s += 1024) base[s] = srt[s];
}

// merge-path the two sorted halves; emit packed (v0<<16|v1) in global order
__launch_bounds__(64)
__global__ void k_mergepath(const unsigned long long* __restrict__ keys,
                            const int* __restrict__ edges, unsigned* __restrict__ pkG) {
    int t = blockIdx.x * 64 + threadIdx.x;
    if (t >= E / 64) return;
    const unsigned long long* A = keys;
    const unsigned long long* B = keys + HALF;
    int d = t * 64;
    int lo = d > HALF ? d - HALF : 0;
    int hi = d < HALF ? d : HALF;
    while (lo < hi) {
        int mid = (lo + hi) >> 1;
        if (A[mid] < B[d - 1 - mid]) lo = mid + 1; else hi = mid;
    }
    int ia = lo, ib = d - lo;
    for (int o = d; o < d + 64; o++) {
        bool takeA = (ib >= HALF) || (ia < HALF && A[ia] < B[ib]);
        unsigned long long r = takeA ? A[ia++] : B[ib++];
        int e = (int)(r & 0xFFFFFFFFull);
        int a = edges[e], b = edges[E + e];
        pkG[o] = ((unsigned)a << 16) | (unsigned)b;
    }
}

// ONE wave: windowed monotone scan; O(1)-per-stage rounds:
// select(ballot) -> fetch(global_load_lds) -> pairwise filter (parallel) ->
// group-parallel apply (1 merge per 4 lanes) -> O(1) refresh (v0->slot map)
__launch_bounds__(64, 1)
__global__ void k_collapse(const unsigned* __restrict__ pkG, unsigned* n32,
                           unsigned* __restrict__ pairsG, int* __restrict__ mcountG,
                           uint8_t* __restrict__ aliveG, float* __restrict__ out) {
    __shared__ unsigned shRows[2 * CAP * ROWU32];   // 32 KB: slot 2k=row v0, 2k+1=row v1
    __shared__ uint8_t  alive[V];                   // 4 KB
    __shared__ uint8_t  shV2S[V];                   // 4 KB: kept v0 -> shRows slot, 0xFF none
    __shared__ unsigned shCand[CAP];
    __shared__ unsigned shConf[CAP];
    const int lane = threadIdx.x;
    for (int v = lane; v < V; v += 64) { alive[v] = 1; shV2S[v] = 0xFF; }
    __syncthreads();

    int cnt = V, mcount = 0;
    bool done = false;

    for (int w = 0; w < E && !done; w += 64) {
        __builtin_amdgcn_s_waitcnt(WAIT_VM0);        // prior window's stores visible
        unsigned pkv = pkG[w + lane];
        const int a = (int)(pkv >> 16), b = (int)(pkv & 0xFFFFu);
        unsigned wv = *(volatile unsigned*)(n32 + a * ROWU32 + (b >> 4));
        unsigned fv = (wv >> ((b & 15) * 2)) & 3u;   // register-tracked 2-bit field
        bool dec = !(alive[a] && alive[b]);          // monotone: false is final

        while (!done) {
            if (!dec && fv != 2u) dec = true;        // monotone reject (final)
            unsigned long long mF = __ballot(!dec);  // undecided == flagged
            if (!mF) break;
            int limit = cnt - TARGET; if (limit > CAP) limit = CAP;
            int flagged = (int)__popcll(mF);
            int nacc = flagged < limit ? flagged : limit;

            // ---- SELECT: first nacc flagged lanes, post to LDS ----
            int myK = -1;
            if (!dec) {
                int rank = (int)__popcll(mF & ((1ull << lane) - 1ull));
                if (rank < limit) { myK = rank; shCand[rank] = pkv; }
            }
            if (lane < CAP) shConf[lane] = 0u;
            __syncthreads();

            // ---- FETCH rows into LDS (drain prior round's stores first) ----
            __builtin_amdgcn_s_waitcnt(WAIT_VM0);
            for (int k = 0; k < nacc; k++) {
                unsigned cp = shCand[k];
                int v0 = (int)(cp >> 16), v1 = (int)(cp & 0xFFFFu);
                __builtin_amdgcn_global_load_lds(
                    (gas1_t)(n32 + v0 * ROWU32 + lane * 4),
                    (las3_t)(shRows + (2 * k) * ROWU32), 16, 0, 0);
                __builtin_amdgcn_global_load_lds(
                    (gas1_t)(n32 + v1 * ROWU32 + lane * 4),
                    (las3_t)(shRows + (2 * k + 1) * ROWU32), 16, 0, 0);
            }
            __builtin_amdgcn_s_waitcnt(WAIT_VM0);
            __syncthreads();

            // ---- FILTER: pairwise (j<k) conflicts, <=4 pairs per lane ----
            for (int pp = lane; pp < CAP * CAP; pp += 64) {
                int k = pp >> 4, j = pp & 15;
                if (j < k && k < nacc) {
                    unsigned cj = shCand[j], ck = shCand[k];
                    int v0j = (int)(cj >> 16), v1j = (int)(cj & 0xFFFFu);
                    int v0k = (int)(ck >> 16), v1k = (int)(ck & 0xFFFFu);
                    // shared endpoints (exact order semantics + disjointness)
                    bool c = (v0k == v0j) || (v0k == v1j) || (v1k == v0j) || (v1k == v1j);
                    // H1: {v0k,v1k} adjacent to v1j (k's rows stale wrt j's update)
                    c |= ((shRows[(2*j+1)*ROWU32 + (v0k >> 4)] >> ((v0k & 15)*2)) & 3u) != 0u;
                    c |= ((shRows[(2*j+1)*ROWU32 + (v1k >> 4)] >> ((v1k & 15)*2)) & 3u) != 0u;
                    // H2: v0j adjacent to v1k (k's xor targets j's rewritten row)
                    c |= ((shRows[(2*k+1)*ROWU32 + (v0j >> 4)] >> ((v0j & 15)*2)) & 3u) != 0u;
                    if (c) atomicOr(&shConf[k], 1u << j);
                }
            }
            __syncthreads();

            // ---- GREEDY keep (replicated, pure VALU): empty conflict row -> kept ----
            unsigned kept = 0u;
            for (int k = 0; k < nacc; k++)
                if (shConf[k] == 0u) kept |= 1u << k;
            int nk = __popc(kept);                   // >=1: k=0 has empty row
            if (myK >= 0 && ((kept >> myK) & 1u)) dec = true;   // my merge applies

            // ---- MARK: alive, v0->slot map, merge log (priority order) ----
            if (lane < nacc && ((kept >> lane) & 1u)) {
                unsigned cp = shCand[lane];
                int v0 = (int)(cp >> 16), v1 = (int)(cp & 0xFFFFu);
                alive[v1] = 0;
                shV2S[v0] = (uint8_t)(2 * lane);
                int r = __popc(kept & ((1u << lane) - 1u));
                pairsG[mcount + r] = cp;
            }
            mcount += nk; cnt -= nk;
            __syncthreads();

            // ---- APPLY: group g = lane>>2 applies kept candidate g ----
            {
                int g = lane >> 2, sub = lane & 3;
                if (g < nacc && ((kept >> g) & 1u)) {
                    unsigned cp = shCand[g];
                    int v0 = (int)(cp >> 16), v1 = (int)(cp & 0xFFFFu);
                    const uint4* rowA = (const uint4*)(shRows + (2 * g) * ROWU32);
                    const uint4* rowB = (const uint4*)(shRows + (2 * g + 1) * ROWU32);
                    int m0u = v0 >> 6, m1u = v1 >> 6;
                    int sh0 = (v0 & 15) * 2, wi0 = v0 >> 4;
                    for (int t = 0; t < 16; t++) {
                        int u = sub * 16 + ((t + lane) & 15);   // bank-spread rotation
                        uint4 ra = rowA[u], rb = rowB[u];
                        uint4 rr;
                        rr.x = ra.x | rb.x | ((ra.x & rb.x & 0xAAAAAAAAu) >> 1);
                        rr.y = ra.y | rb.y | ((ra.y & rb.y & 0xAAAAAAAAu) >> 1);
                        rr.z = ra.z | rb.z | ((ra.z & rb.z & 0xAAAAAAAAu) >> 1);
                        rr.w = ra.w | rb.w | ((ra.w & rb.w & 0xAAAAAAAAu) >> 1);
                        if (u == m0u) andf(rr, (v0 >> 4) & 3, ~(3u << ((v0 & 15) * 2)));
                        if (u == m1u) andf(rr, (v1 >> 4) & 3, ~(3u << ((v1 & 15) * 2)));
                        ((uint4*)(n32 + v0 * ROWU32))[u] = rr;
                        ((uint4*)shRows)[(2 * g) * (ROWU32 / 4) + u] = rr;  // for refresh
                        // column fixups via atomicXor (symmetry gives old value)
#pragma unroll
                        for (int c = 0; c < 4; c++) {
                            unsigned bb = getf(rb, c);
                            if (!bb) continue;
                            unsigned aa = getf(ra, c), vvv = getf(rr, c);
                            int xbase = (u << 6) + (c << 4);
                            unsigned tt = bb;
                            while (tt) {
                                int q = (__ffs(tt) - 1) >> 1;
                                tt &= ~(3u << (q * 2));
                                int x = xbase + q;
                                if (x != v0 && x != v1) {
                                    unsigned dx =
                                        (((aa >> (q*2)) ^ (vvv >> (q*2))) & 3u) << sh0;
                                    if (dx) atomicXor(n32 + x * ROWU32 + wi0, dx);
                                }
                            }
                        }
                    }
                }
            }
            __syncthreads();

            // ---- REFRESH: O(1) per lane via alive + v0->slot map ----
            if (!dec) {
                if (!alive[a] || !alive[b]) dec = true;   // endpoint died (final)
                else {
                    int s = shV2S[a];
                    if (s != 0xFF)
                        fv = (shRows[s * ROWU32 + (b >> 4)] >> ((b & 15) * 2)) & 3u;
                    else {
                        s = shV2S[b];
                        if (s != 0xFF)
                            fv = (shRows[s * ROWU32 + (a >> 4)] >> ((a & 15) * 2)) & 3u;
                    }
                }
            }
            __syncthreads();

            // ---- CLEAR v0->slot map entries ----
            if (lane < nacc && ((kept >> lane) & 1u))
                shV2S[(int)(shCand[lane] >> 16)] = 0xFF;

            if (cnt == TARGET) done = true;
        }
    }

    for (int v = lane; v < V; v += 64) {
        uint8_t ao = alive[v];
        aliveG[v] = ao;
        out[V * D + v] = ao ? 1.0f : 0.0f;
    }
    if (lane == 0) { mcountG[0] = mcount; out[V * D + V] = (float)cnt; }
}

// Replay merge forest: per-vertex (root, weight) then scatter-add w*f[v] into out[root].
__launch_bounds__(256)
__global__ void k_apply(const float* __restrict__ f, const unsigned* __restrict__ pairsG,
                        const int* __restrict__ mcountG, float* __restrict__ out) {
    __shared__ unsigned pl[MAXM];
    __shared__ int rootL[256];
    __shared__ float wL[256];
    const int tid = threadIdx.x;
    const int mc = mcountG[0];
    for (int j = tid; j < mc; j += 256) pl[j] = pairsG[j];
    __syncthreads();
    int cur = blockIdx.x * 256 + tid;
    float w = 1.0f;
    for (int j = 0; j < mc; j++) {
        unsigned p = pl[j];
        int v0 = (int)(p >> 16), v1 = (int)(p & 0xFFFFu);
        if (cur == v1) { cur = v0; w *= 0.5f; }
        else if (cur == v0) w *= 0.5f;
    }
    rootL[tid] = cur;
    wL[tid] = w;
    __syncthreads();
    const int sub = tid >> 7;
    const int d = tid & 127;
    for (int s = 0; s < 256; s += 2) {
        int idx = s + sub;
        int vv = blockIdx.x * 256 + idx;
        atomicAdd(&out[rootL[idx] * D + d], wL[idx] * f[vv * D + d]);
    }
}

extern "C" void kernel_launch(void* const* d_in, const int* in_sizes, int n_in,
                              void* d_out, int out_size, void* d_ws, size_t ws_size,
                              hipStream_t stream) {
    (void)in_sizes; (void)n_in; (void)out_size; (void)ws_size;
    const float* features = (const float*)d_in[0];
    const int* edges = (const int*)d_in[1];
    uint8_t* ws = (uint8_t*)d_ws;
    unsigned* n32 = (unsigned*)(ws + WS_N);
    float* pri = (float*)(ws + WS_PRI);
    unsigned long long* keys = (unsigned long long*)(ws + WS_KEYS);
    unsigned* pkG = (unsigned*)(ws + WS_PK);
    unsigned* pairsG = (unsigned*)(ws + WS_PAIRS);
    int* mcountG = (int*)(ws + WS_MCOUNT);
    uint8_t* aliveG = ws + WS_ALIVE;
    float* out = (float*)d_out;

    hipMemsetAsync(n32, 0, (size_t)V * ROWU32 * 4, stream);
    hipMemsetAsync(out, 0, (size_t)V * D * sizeof(float), stream);
    k_pri<<<(V + 255) / 256, 256, 0, stream>>>(features, pri);
    k_scatter<<<(E + 255) / 256, 256, 0, stream>>>(edges, n32);
    k_keys<<<(NPAD + 255) / 256, 256, 0, stream>>>(edges, pri, keys);
    k_sort2<<<2, 1024, 0, stream>>>(keys);
    k_mergepath<<<(E / 64 + 63) / 64, 64, 0, stream>>>(keys, edges, pkG);
    k_collapse<<<1, 64, 0, stream>>>(pkG, n32, pairsG, mcountG, aliveG, out);
    k_apply<<<V / 256, 256, 0, stream>>>(features, pairsG, mcountG, out);
}